// Round 1
// baseline (51009.293 us; speedup 1.0000x reference)
//
#include <hip/hip_runtime.h>
#include <math.h>

// NCA: B=8, H=W=256, C=16, 16 steps.
// Round 0: correct fp32 implementation (semantics validation baseline).
//   step k: step_main  (conv/pools/perc + MLP -> x_mid, alpha plane, prelife)
//           step_mask  (life = prelife & maxpool3(alpha_new)>0.1; x *= life*valid)
// Ping-pong: X_k dst = (k odd ? ws.xA : d_out); X_16 -> d_out.
// ws layout (floats): xA[8388608] | alpha[524288] | prelife[524288] | filt[~384] | W0T[32768]
// total ~37.9 MB of d_ws.

#define HW 256
#define NPIX (8*HW*HW)   // 524288

__device__ __forceinline__ float4 f4max(float4 a, float4 b) {
    return make_float4(fmaxf(a.x,b.x), fmaxf(a.y,b.y), fmaxf(a.z,b.z), fmaxf(a.w,b.w));
}

// Precompute sobel bank (6 filters, 7x7, normalized) and W0^T (256x128).
__global__ void init_kernel(const float* __restrict__ W0,
                            float* __restrict__ W0T,
                            float* __restrict__ filt) {
    int t = blockIdx.x * blockDim.x + threadIdx.x;
    int nthreads = gridDim.x * blockDim.x;
    for (int idx = t; idx < 256*128; idx += nthreads) {
        int j = idx >> 7, k = idx & 127;
        W0T[idx] = W0[k*256 + j];
    }
    if (t < 6) {
        // filter order: gx3, gy3, gx5, gy5, gx7, gy7  (matches ks ordering)
        int f = t;
        int size = 3 + 2*(f >> 1);
        int p0 = (7 - size) >> 1;
        int isY = f & 1;
        float vals[49];
        float norm = 0.f;
        for (int a = 0; a < 7; a++) {
            for (int b = 0; b < 7; b++) {
                float v = 0.f;
                if (a >= p0 && a < p0+size && b >= p0 && b < p0+size) {
                    float fy = (float)(a - 3), fx = (float)(b - 3);
                    float den = fx*fx + fy*fy;
                    if (den == 0.f) den = 1.f;   // denom[s,s]=1
                    v = (isY ? fy : fx) / den;
                }
                vals[a*7+b] = v;
                norm += fabsf(v);
            }
        }
        float inv = 1.f / norm;
        for (int i = 0; i < 49; i++) filt[f*49 + i] = vals[i] * inv;
    }
}

// One 8x8 pixel tile per block, 256 threads: thread = (pixel p 0..63, chan-quad q 0..3).
__launch_bounds__(256, 2)
__global__ void step_main(const float* __restrict__ x,
                          float* __restrict__ xmid,
                          float* __restrict__ alpha_out,
                          float* __restrict__ prelife_out,
                          const float* __restrict__ filt_g,
                          const float* __restrict__ W0T,
                          const float* __restrict__ b0,
                          const float* __restrict__ W1,
                          const float* __restrict__ stoch_s) {
    __shared__ float xs[14*14*20];     // 8+6 halo, channel dim padded 16->20 (bank spread)
    __shared__ float filt_s[294];
    __shared__ float perc[64*132];     // 128-ch percept per pixel, +4 pad
    __shared__ float dxpart[4*64*20];  // per-q partial dx (16 used of 20)

    const int t   = threadIdx.x;
    const int b   = blockIdx.z;
    const int ty0 = blockIdx.y * 8;
    const int tx0 = blockIdx.x * 8;

    for (int i = t; i < 294; i += 256) filt_s[i] = filt_g[i];

    // stage x tile + halo (zero pad -> matches conv's zero padding; pools use
    // clamped-range max so OOB zeros are never consulted there)
    for (int v = t; v < 784; v += 256) {          // 14*14*4 float4s
        int c4  = v & 3;
        int cell = v >> 2;
        int ly = cell / 14;
        int lx = cell - ly*14;
        int gy = ty0 + ly - 3, gx = tx0 + lx - 3;
        float4 val = make_float4(0.f,0.f,0.f,0.f);
        if ((unsigned)gy < 256u && (unsigned)gx < 256u)
            val = *(const float4*)&x[((((b<<8) + gy)<<8) + gx)*16 + (c4<<2)];
        *(float4*)&xs[cell*20 + (c4<<2)] = val;
    }
    __syncthreads();

    const int p  = t & 63;
    const int q  = t >> 6;
    const int py = p >> 3, px = p & 7;
    const int gy = ty0 + py, gx = tx0 + px;
    const int q4 = q << 2;

    // phase 1: conv (6 filters x 4 channels) + pool5 + (q==0) pool3 alpha
    float4 y4[6];
    #pragma unroll
    for (int f = 0; f < 6; f++) y4[f] = make_float4(0.f,0.f,0.f,0.f);
    float4 m5 = make_float4(-INFINITY,-INFINITY,-INFINITY,-INFINITY);
    float pre = -INFINITY;

    #pragma unroll
    for (int a = 0; a < 7; a++) {
        #pragma unroll
        for (int bb = 0; bb < 7; bb++) {
            float4 xv = *(const float4*)&xs[((py+a)*14 + (px+bb))*20 + q4];
            #pragma unroll
            for (int f = 0; f < 6; f++) {
                float w = filt_s[f*49 + a*7 + bb];
                y4[f].x = fmaf(w, xv.x, y4[f].x);
                y4[f].y = fmaf(w, xv.y, y4[f].y);
                y4[f].z = fmaf(w, xv.z, y4[f].z);
                y4[f].w = fmaf(w, xv.w, y4[f].w);
            }
            int dy = a - 3, dxo = bb - 3;
            bool inb = ((unsigned)(gy+dy) < 256u) && ((unsigned)(gx+dxo) < 256u);
            if (inb && dy >= -2 && dy <= 2 && dxo >= -2 && dxo <= 2)
                m5 = f4max(m5, xv);
            if (q == 0 && inb && dy >= -1 && dy <= 1 && dxo >= -1 && dxo <= 1)
                pre = fmaxf(pre, xv.w);        // alpha = channel 3 = .w of quad 0
        }
    }

    // perc layout: [0:16)=x, [16+f*16+c)=y (f-major matches the reference
    // (...,C,6)->(...,6,C) transpose), [112:128)=pool5
    float4 xc = *(const float4*)&xs[((py+3)*14 + (px+3))*20 + q4];
    *(float4*)&perc[p*132 + q4] = xc;
    #pragma unroll
    for (int f = 0; f < 6; f++)
        *(float4*)&perc[p*132 + 16 + f*16 + q4] = y4[f];
    *(float4*)&perc[p*132 + 112 + q4] = m5;

    const int pix = (b << 16) + (gy << 8) + gx;
    if (q == 0)
        prelife_out[pix] = (pre > 0.1f) ? 1.f : 0.f;
    __syncthreads();

    // phase 2: GEMV. thread (p,q) computes h[j] for j in [64q,64q+64) and
    // accumulates its partial dx[16]. perc hoisted to VGPRs; W0T/W1/b0 are
    // wave-uniform (broadcast) loads.
    float4 pv[32];
    #pragma unroll
    for (int i = 0; i < 32; i++)
        pv[i] = *(const float4*)&perc[p*132 + (i << 2)];

    float4 d0 = make_float4(0,0,0,0), d1 = d0, d2 = d0, d3 = d0;
    for (int i = 0; i < 64; i++) {
        int j = (q << 6) + i;
        float z = b0[j];
        const float4* wc = (const float4*)&W0T[j << 7];
        #pragma unroll
        for (int k = 0; k < 32; k++) {
            float4 w = wc[k];
            z = fmaf(pv[k].x, w.x, z);
            z = fmaf(pv[k].y, w.y, z);
            z = fmaf(pv[k].z, w.z, z);
            z = fmaf(pv[k].w, w.w, z);
        }
        float h = fmaxf(z, 0.f);
        const float4* w1 = (const float4*)&W1[j << 4];
        float4 a0 = w1[0], a1 = w1[1], a2 = w1[2], a3 = w1[3];
        d0.x = fmaf(h, a0.x, d0.x); d0.y = fmaf(h, a0.y, d0.y);
        d0.z = fmaf(h, a0.z, d0.z); d0.w = fmaf(h, a0.w, d0.w);
        d1.x = fmaf(h, a1.x, d1.x); d1.y = fmaf(h, a1.y, d1.y);
        d1.z = fmaf(h, a1.z, d1.z); d1.w = fmaf(h, a1.w, d1.w);
        d2.x = fmaf(h, a2.x, d2.x); d2.y = fmaf(h, a2.y, d2.y);
        d2.z = fmaf(h, a2.z, d2.z); d2.w = fmaf(h, a2.w, d2.w);
        d3.x = fmaf(h, a3.x, d3.x); d3.y = fmaf(h, a3.y, d3.y);
        d3.z = fmaf(h, a3.z, d3.z); d3.w = fmaf(h, a3.w, d3.w);
    }
    {
        float* base = &dxpart[(q*64 + p)*20];
        *(float4*)&base[0]  = d0;
        *(float4*)&base[4]  = d1;
        *(float4*)&base[8]  = d2;
        *(float4*)&base[12] = d3;
    }
    __syncthreads();

    // combine partials over q, apply fire mask, write x_mid
    const int pp  = t >> 2;
    const int c4o = (t & 3) << 2;
    float4 dsum = make_float4(0,0,0,0);
    #pragma unroll
    for (int qq = 0; qq < 4; qq++) {
        float4 v = *(const float4*)&dxpart[(qq*64 + pp)*20 + c4o];
        dsum.x += v.x; dsum.y += v.y; dsum.z += v.z; dsum.w += v.w;
    }
    const int ppy = pp >> 3, ppx = pp & 7;
    const int gy2 = ty0 + ppy, gx2 = tx0 + ppx;
    const int pix2 = (b << 16) + (gy2 << 8) + gx2;
    float fire = (stoch_s[pix2] > 0.5f) ? 1.f : 0.f;
    float4 xc2 = *(const float4*)&xs[((ppy+3)*14 + (ppx+3))*20 + c4o];
    float4 xn;
    xn.x = fmaf(fire, dsum.x, xc2.x);
    xn.y = fmaf(fire, dsum.y, xc2.y);
    xn.z = fmaf(fire, dsum.z, xc2.z);
    xn.w = fmaf(fire, dsum.w, xc2.w);
    *(float4*)&xmid[pix2*16 + c4o] = xn;
    if ((t & 3) == 0) alpha_out[pix2] = xn.w;   // channel 3
}

// In-place life masking: reads alpha_new from the separate plane (race-free),
// writes only its own pixel.
__global__ void step_mask(float* __restrict__ xbuf,
                          const float* __restrict__ alpha,
                          const float* __restrict__ prelife,
                          const float* __restrict__ valid) {
    int pix = blockIdx.x * 256 + threadIdx.x;
    int b = pix >> 16;
    int y = (pix >> 8) & 255;
    int x = pix & 255;
    float m = -INFINITY;
    #pragma unroll
    for (int dy = -1; dy <= 1; dy++) {
        #pragma unroll
        for (int dxo = -1; dxo <= 1; dxo++) {
            int yy = y + dy, xx = x + dxo;
            if ((unsigned)yy < 256u && (unsigned)xx < 256u)
                m = fmaxf(m, alpha[(b << 16) + (yy << 8) + xx]);
        }
    }
    float life = (prelife[pix] != 0.f && m > 0.1f) ? 1.f : 0.f;
    float s = life * valid[pix];
    float4* xp = (float4*)&xbuf[pix << 4];
    #pragma unroll
    for (int i = 0; i < 4; i++) {
        float4 v = xp[i];
        v.x *= s; v.y *= s; v.z *= s; v.w *= s;
        xp[i] = v;
    }
}

extern "C" void kernel_launch(void* const* d_in, const int* in_sizes, int n_in,
                              void* d_out, int out_size, void* d_ws, size_t ws_size,
                              hipStream_t stream) {
    const float* x0    = (const float*)d_in[0];
    const float* valid = (const float*)d_in[1];
    const float* stoch = (const float*)d_in[2];
    const float* W0    = (const float*)d_in[3];
    const float* b0    = (const float*)d_in[4];
    const float* W1    = (const float*)d_in[5];
    // d_in[6] = steps (fixed at 16 by setup_inputs)

    float* ws      = (float*)d_ws;
    float* xA      = ws;                 // 8388608 floats
    float* alpha   = ws + 8388608;       // 524288
    float* prelife = ws + 8912896;       // 524288
    float* filt    = ws + 9437184;       // 294 (+pad)
    float* W0T     = ws + 9437568;       // 32768
    float* out     = (float*)d_out;

    init_kernel<<<64, 256, 0, stream>>>(W0, W0T, filt);

    const float* src = x0;
    for (int k = 1; k <= 16; k++) {
        float* dst = (k & 1) ? xA : out;   // step 16 (even) lands in d_out
        step_main<<<dim3(32,32,8), 256, 0, stream>>>(
            src, dst, alpha, prelife, filt, W0T, b0, W1,
            stoch + (size_t)(k-1)*NPIX);
        step_mask<<<NPIX/256, 256, 0, stream>>>(dst, alpha, prelife, valid);
        src = dst;
    }
}